// Round 13
// baseline (584.505 us; speedup 1.0000x reference)
//
#include <hip/hip_runtime.h>
#include <hip/hip_bf16.h>
#include <cstdint>

// ---- problem constants (HierarchicalBrainGNN) ----
constexpr int NN   = 20000;          // nodes
constexpr int NNP  = 20032;          // padded to 313*64 (GEMM reads A rows unguarded)
constexpr int NE   = 320000;         // edges before self loops
constexpr int ETOT = NE + NN;        // with self loops
constexpr int BG   = 8;              // graphs
constexpr int FIN  = 100;
constexpr int HID  = 256;
constexpr int H    = 4;              // heads
constexpr float SLOPE  = 0.2f;
constexpr float LN_EPS = 1e-5f;

#define DEVFN __device__ __forceinline__

typedef __bf16 bf16x8 __attribute__((ext_vector_type(8)));
typedef float  f32x4  __attribute__((ext_vector_type(4)));
typedef float  f32x2  __attribute__((ext_vector_type(2)));

DEVFN float lrelu(float v) { return v > 0.f ? v : SLOPE * v; }
// fp32 -> bf16 bits, round-nearest-even (finite inputs)
DEVFN ushort f2bf(float f) {
    unsigned u = __float_as_uint(f);
    return (ushort)((u + 0x7fffu + ((u >> 16) & 1u)) >> 16);
}
DEVFN float bf_lo(unsigned u) { return __uint_as_float(u << 16); }
DEVFN float bf_hi(unsigned u) { return __uint_as_float(u & 0xffff0000u); }
DEVFN float bf2f(unsigned u) { return __uint_as_float(u << 16); }

// ---------------- utility ----------------
__global__ void zero_u32(uint32_t* __restrict__ p, int n) {
    int i = blockIdx.x * blockDim.x + threadIdx.x;
    if (i < n) p[i] = 0u;
}

// single-block scan, 4 values/thread (int4), wave-shuffle based; 5 chunks of 4096
__global__ void scan_kernel(const int* __restrict__ deg, int* __restrict__ rowptr) {
    __shared__ int wsum[16];
    __shared__ int woff[16];
    __shared__ int ctot;
    const int lane = threadIdx.x & 63;
    const int wv   = threadIdx.x >> 6;
    const int4* deg4 = (const int4*)deg;        // NN/4 = 5000 int4 (deg 256-aligned)
    int carry = 0;
    for (int base4 = 0; base4 < NN / 4; base4 += 1024) {
        int i4 = base4 + threadIdx.x;
        int4 v = make_int4(0, 0, 0, 0);
        if (i4 < NN / 4) v = deg4[i4];
        int t0 = v.x, t1 = t0 + v.y, t2 = t1 + v.z, t3 = t2 + v.w;  // thread-local incl
        int s = t3;
#pragma unroll
        for (int off = 1; off < 64; off <<= 1) {
            int t = __shfl_up(s, off);
            if (lane >= off) s += t;
        }
        if (lane == 63) wsum[wv] = s;
        __syncthreads();
        if (wv == 0 && lane < 16) {
            int ws = wsum[lane];
            int sc = ws;
#pragma unroll
            for (int off = 1; off < 16; off <<= 1) {
                int t = __shfl_up(sc, off);
                if (lane >= off) sc += t;
            }
            woff[lane] = sc - ws;
            if (lane == 15) ctot = sc;
        }
        __syncthreads();
        if (i4 < NN / 4) {
            int be = carry + woff[wv] + (s - t3);   // exclusive prefix of this thread's 4
            rowptr[4 * i4 + 0] = be;
            rowptr[4 * i4 + 1] = be + t0;
            rowptr[4 * i4 + 2] = be + t1;
            rowptr[4 * i4 + 3] = be + t2;
        }
        carry += ctot;
        __syncthreads();
    }
    if (threadIdx.x == 0) rowptr[NN] = carry;
}

__global__ void scatter_edges(const int* __restrict__ ei, const int* __restrict__ rowptr,
                              int* __restrict__ fill, int* __restrict__ esrc) {
    int k = blockIdx.x * blockDim.x + threadIdx.x;
    if (k >= ETOT) return;
    int s, d;
    if (k < NE) { s = ei[k]; d = ei[NE + k]; }
    else        { s = k - NE; d = k - NE; }
    int pos = rowptr[d] + atomicAdd(&fill[d], 1);
    esrc[pos] = s;
}

// --- fused convert (+count_deg): xpad + 5 transposed bf16 weights + degree count ---
constexpr int CXN  = NN * 128;
constexpr int CWI  = 256 * 128;
constexpr int CW0  = 1024 * 256;
constexpr int CW1  = 512 * 256;
constexpr int CW2  = 256 * 128;
constexpr int CW3  = 128 * 64;
constexpr int CTOT = CXN + CWI + CW0 + CW1 + CW2 + CW3;
constexpr int CALL = CTOT + ETOT;          // + count_deg range

__global__ void conv_all(const float* __restrict__ x, const float* __restrict__ Wi,
                         const float* __restrict__ W0, const float* __restrict__ W1,
                         const float* __restrict__ W2, const float* __restrict__ W3,
                         const int* __restrict__ ei, int* __restrict__ deg,
                         ushort* __restrict__ xpad, ushort* __restrict__ wti,
                         ushort* __restrict__ wt0, ushort* __restrict__ wt1,
                         ushort* __restrict__ wt2, ushort* __restrict__ wt3) {
    int id = blockIdx.x * blockDim.x + threadIdx.x;
    if (id < CXN) {
        int n = id >> 7, k = id & 127;
        xpad[id] = (k < FIN) ? f2bf(x[(size_t)n * FIN + k]) : (ushort)0;
        return;
    }
    id -= CXN;
    if (id < CWI) { int n = id / 128, k = id - n * 128;
        wti[id] = (k < FIN) ? f2bf(Wi[(size_t)k * 256 + n]) : (ushort)0; return; }
    id -= CWI;
    if (id < CW0) { int n = id / 256, k = id - n * 256;
        wt0[id] = f2bf(W0[(size_t)k * 1024 + n]); return; }
    id -= CW0;
    if (id < CW1) { int n = id / 256, k = id - n * 256;
        wt1[id] = f2bf(W1[(size_t)k * 512 + n]); return; }
    id -= CW1;
    if (id < CW2) { int n = id / 128, k = id - n * 128;
        wt2[id] = f2bf(W2[(size_t)k * 256 + n]); return; }
    id -= CW2;
    if (id < CW3) { int n = id / 64, k = id - n * 64;
        wt3[id] = f2bf(W3[(size_t)k * 128 + n]); return; }
    id -= CW3;
    if (id < ETOT) {     // count_deg (deg pre-zeroed by the zero kernel)
        int d = (id < NE) ? ei[NE + id] : (id - NE);
        atomicAdd(&deg[d], 1);
    }
}

// ---------------- MFMA bf16 GEMM + fused attention-logit epilogue --------------------
// A fragments read DIRECTLY from global (L1-resident). Only B staged in LDS.
// B is REGISTER DOUBLE-BUFFERED across the CT col-tile loop: next tile's chunk is
// loaded into VGPRs right after the barrier, overlapping global latency with MFMAs.
// __launch_bounds__(256,4) caps VGPR at 128 to keep 4 blocks/CU.
// if !AL: Cout = bf16[M,NC] = relu(A@Wt^T + bias) (input layer)
// if  AL: Cout = fp8 e4m3 [M,NC] (hproj); al_s/al_d from exact fp32 accumulators
// A-frag: A[m=lane&15][k=quad*8+j]; B-frag: B[k][n=lane&15];
// D: col=lane&15, row=quad*4+reg  (verified round 2)
template <int K, int NC, int CT, bool BR, bool AL>
__launch_bounds__(256, 4)
__global__ void gemm_mfma(const ushort* __restrict__ A, const ushort* __restrict__ Wt,
                          const float* __restrict__ bias, void* __restrict__ Cout,
                          const float* __restrict__ a_s, const float* __restrict__ a_d,
                          float* __restrict__ al_s, float* __restrict__ al_d, int M) {
    constexpr int LDK = K + 8;
    constexpr int DO_AL = NC / H;
    constexpr int CH = K / 8;              // uint4 chunks per B row
    constexpr int NB = (64 * CH) / 256;    // uint4 per thread to stage one B tile
    __shared__ ushort Bs[64 * LDK];
    const int row0 = blockIdx.x * 64;
    const int colbase = blockIdx.y * (64 * CT);
    const int tid = threadIdx.x;
    const int wave = tid >> 6;
    const int lane = tid & 63;
    const int m = lane & 15;
    const int q = lane >> 4;
    const ushort* Ap  = A + (size_t)(row0 + wave * 16 + m) * K + q * 8;  // rows < NNP
    const ushort* bp0 = &Bs[(0 * 16 + m) * LDK + q * 8];
    const ushort* bp1 = &Bs[(1 * 16 + m) * LDK + q * 8];
    const ushort* bp2 = &Bs[(2 * 16 + m) * LDK + q * 8];
    const ushort* bp3 = &Bs[(3 * 16 + m) * LDK + q * 8];
    const int grow0 = row0 + wave * 16 + q * 4;

    uint4 breg[NB];
#pragma unroll
    for (int j = 0; j < NB; j++) {
        int i = j * 256 + tid;
        int r = i / CH, cc = i - r * CH;
        breg[j] = *(const uint4*)(Wt + (size_t)(colbase + r) * K + cc * 8);
    }

    for (int ct = 0; ct < CT; ct++) {
        const int col0 = colbase + ct * 64;
        // commit prefetched B tile to LDS
#pragma unroll
        for (int j = 0; j < NB; j++) {
            int i = j * 256 + tid;
            int r = i / CH, cc = i - r * CH;
            *(uint4*)(&Bs[r * LDK + cc * 8]) = breg[j];
        }
        __syncthreads();
        // prefetch next tile (in flight during MFMAs below)
        if (ct + 1 < CT) {
#pragma unroll
            for (int j = 0; j < NB; j++) {
                int i = j * 256 + tid;
                int r = i / CH, cc = i - r * CH;
                breg[j] = *(const uint4*)(Wt + (size_t)(col0 + 64 + r) * K + cc * 8);
            }
        }
        f32x4 acc0 = {0.f, 0.f, 0.f, 0.f}, acc1 = acc0, acc2 = acc0, acc3 = acc0;
#pragma unroll
        for (int kk = 0; kk < K / 32; kk++) {
            bf16x8 a = *(const bf16x8*)(Ap + kk * 32);
            acc0 = __builtin_amdgcn_mfma_f32_16x16x32_bf16(a, *(const bf16x8*)(bp0 + kk * 32), acc0, 0, 0, 0);
            acc1 = __builtin_amdgcn_mfma_f32_16x16x32_bf16(a, *(const bf16x8*)(bp1 + kk * 32), acc1, 0, 0, 0);
            acc2 = __builtin_amdgcn_mfma_f32_16x16x32_bf16(a, *(const bf16x8*)(bp2 + kk * 32), acc2, 0, 0, 0);
            acc3 = __builtin_amdgcn_mfma_f32_16x16x32_bf16(a, *(const bf16x8*)(bp3 + kk * 32), acc3, 0, 0, 0);
        }
        if (!AL) {
            ushort* Cb = (ushort*)Cout + (size_t)grow0 * NC + col0 + m;
            float b0 = 0, b1 = 0, b2 = 0, b3 = 0;
            if (BR) {
                b0 = bias[col0 + m];      b1 = bias[col0 + m + 16];
                b2 = bias[col0 + m + 32]; b3 = bias[col0 + m + 48];
            }
#pragma unroll
            for (int r = 0; r < 4; r++) {
                if (grow0 + r < M) {
                    float v0 = acc0[r], v1 = acc1[r], v2 = acc2[r], v3 = acc3[r];
                    if (BR) {
                        v0 = fmaxf(v0 + b0, 0.f); v1 = fmaxf(v1 + b1, 0.f);
                        v2 = fmaxf(v2 + b2, 0.f); v3 = fmaxf(v3 + b3, 0.f);
                    }
                    Cb[(size_t)r * NC + 0]  = f2bf(v0);
                    Cb[(size_t)r * NC + 16] = f2bf(v1);
                    Cb[(size_t)r * NC + 32] = f2bf(v2);
                    Cb[(size_t)r * NC + 48] = f2bf(v3);
                }
            }
        } else {
            uchar* Cb = (uchar*)Cout + (size_t)grow0 * NC + col0 + m;
#pragma unroll
            for (int r = 0; r < 4; r++) {
                if (grow0 + r < M) {
                    int pk01 = __builtin_amdgcn_cvt_pk_fp8_f32(acc0[r], acc1[r], 0, false);
                    int pk23 = __builtin_amdgcn_cvt_pk_fp8_f32(acc2[r], acc3[r], 0, false);
                    Cb[(size_t)r * NC + 0]  = (uchar)(pk01 & 0xff);
                    Cb[(size_t)r * NC + 16] = (uchar)((pk01 >> 8) & 0xff);
                    Cb[(size_t)r * NC + 32] = (uchar)(pk23 & 0xff);
                    Cb[(size_t)r * NC + 48] = (uchar)((pk23 >> 8) & 0xff);
                }
            }
            float asv[4], adv[4];
#pragma unroll
            for (int t = 0; t < 4; t++) {
                int gc = col0 + m + 16 * t;
                asv[t] = a_s[gc];
                adv[t] = a_d[gc];
            }
            const int h_lo = col0 / DO_AL;
            const int h_hi = (col0 + 32) / DO_AL;
#pragma unroll
            for (int r = 0; r < 4; r++) {
                float ps0 = acc0[r] * asv[0] + acc1[r] * asv[1];
                float ps1 = acc2[r] * asv[2] + acc3[r] * asv[3];
                float pd0 = acc0[r] * adv[0] + acc1[r] * adv[1];
                float pd1 = acc2[r] * adv[2] + acc3[r] * adv[3];
#pragma unroll
                for (int off = 1; off < 16; off <<= 1) {
                    ps0 += __shfl_xor(ps0, off);
                    ps1 += __shfl_xor(ps1, off);
                    pd0 += __shfl_xor(pd0, off);
                    pd1 += __shfl_xor(pd1, off);
                }
                if (m == 0 && grow0 + r < M) {
                    if (h_lo == h_hi) {
                        atomicAdd(&al_s[(grow0 + r) * H + h_lo], ps0 + ps1);
                        atomicAdd(&al_d[(grow0 + r) * H + h_lo], pd0 + pd1);
                    } else {
                        atomicAdd(&al_s[(grow0 + r) * H + h_lo], ps0);
                        atomicAdd(&al_s[(grow0 + r) * H + h_hi], ps1);
                        atomicAdd(&al_d[(grow0 + r) * H + h_lo], pd0);
                        atomicAdd(&al_d[(grow0 + r) * H + h_hi], pd1);
                    }
                }
            }
        }
        __syncthreads();   // all waves done reading Bs before restage
    }
}

// ---------------- fused segment softmax: one wave per dst, writes normalized alpha ----------
__global__ void softmax_csr(const int* __restrict__ rowptr, const int* __restrict__ esrc,
                            const float* __restrict__ al_s, const float* __restrict__ al_d,
                            float4* __restrict__ alpha) {
    int wid = (blockIdx.x * blockDim.x + threadIdx.x) >> 6;
    int lane = threadIdx.x & 63;
    if (wid >= NN) return;
    int p0 = rowptr[wid], p1 = rowptr[wid + 1];
    float4 d4 = ((const float4*)al_d)[wid];
    float m0 = -1e30f, m1 = -1e30f, m2 = -1e30f, m3 = -1e30f;
    for (int p = p0 + lane; p < p1; p += 64) {
        int s = esrc[p];
        float4 s4 = ((const float4*)al_s)[s];
        m0 = fmaxf(m0, lrelu(s4.x + d4.x));
        m1 = fmaxf(m1, lrelu(s4.y + d4.y));
        m2 = fmaxf(m2, lrelu(s4.z + d4.z));
        m3 = fmaxf(m3, lrelu(s4.w + d4.w));
    }
#pragma unroll
    for (int off = 32; off > 0; off >>= 1) {
        m0 = fmaxf(m0, __shfl_xor(m0, off));
        m1 = fmaxf(m1, __shfl_xor(m1, off));
        m2 = fmaxf(m2, __shfl_xor(m2, off));
        m3 = fmaxf(m3, __shfl_xor(m3, off));
    }
    float s0 = 0.f, s1 = 0.f, s2 = 0.f, s3 = 0.f;
    for (int p = p0 + lane; p < p1; p += 64) {
        int s = esrc[p];
        float4 s4 = ((const float4*)al_s)[s];
        s0 += __expf(lrelu(s4.x + d4.x) - m0);
        s1 += __expf(lrelu(s4.y + d4.y) - m1);
        s2 += __expf(lrelu(s4.z + d4.z) - m2);
        s3 += __expf(lrelu(s4.w + d4.w) - m3);
    }
#pragma unroll
    for (int off = 32; off > 0; off >>= 1) {
        s0 += __shfl_xor(s0, off);
        s1 += __shfl_xor(s1, off);
        s2 += __shfl_xor(s2, off);
        s3 += __shfl_xor(s3, off);
    }
    // fold head-mean 1/H into alpha
    float i0 = 0.25f / (s0 + 1e-16f), i1 = 0.25f / (s1 + 1e-16f);
    float i2 = 0.25f / (s2 + 1e-16f), i3 = 0.25f / (s3 + 1e-16f);
    for (int p = p0 + lane; p < p1; p += 64) {
        int s = esrc[p];
        float4 s4 = ((const float4*)al_s)[s];
        alpha[p] = make_float4(__expf(lrelu(s4.x + d4.x) - m0) * i0,
                               __expf(lrelu(s4.y + d4.y) - m1) * i1,
                               __expf(lrelu(s4.z + d4.z) - m2) * i2,
                               __expf(lrelu(s4.w + d4.w) - m3) * i3);
    }
}

// ------- WAVE-PER-NODE aggregate: fp8 gather, 2-wide x 2-deep pipeline -------
// Zero LDS, zero __syncthreads. 4 independent waves/block (one node each).
// SL = H*DO/16 lanes per edge row (one uint4 = 16 fp8 ch per lane);
// EPI = 64/SL edge groups; 2 edges consumed + 2 prefetched per iteration.
template <int DO, bool RESID>
__launch_bounds__(256)
__global__ void aggregate(const uchar* __restrict__ hproj, const int* __restrict__ rowptr,
                          const int* __restrict__ esrc, const float4* __restrict__ alpha,
                          const float* __restrict__ bias, const float* __restrict__ gamma,
                          const float* __restrict__ beta, const ushort* __restrict__ hprev,
                          ushort* __restrict__ hout) {
    constexpr int HDO = H * DO;
    constexpr int SL  = HDO / 16;          // lanes per edge row: 64/32/16/8
    constexpr int EPI = 64 / SL;           // edge groups per wave: 1/2/4/8
    constexpr int HL  = DO / 16;           // lane classes: 16/8/4/2
    const int wave = threadIdx.x >> 6;
    const int lane = threadIdx.x & 63;
    const int n = blockIdx.x * 4 + wave;   // NN=20000 = 5000*4 exactly
    const int e  = lane / SL;
    const int sl = lane - e * SL;
    const int hsel = sl / HL;              // head of this lane's 16 channels
    const int p0 = rowptr[n], p1 = rowptr[n + 1];
    const uint4* hp4 = (const uint4*)hproj;

    f32x2 acc2[8];
#pragma unroll
    for (int j = 0; j < 8; j++) acc2[j] = f32x2{0.f, 0.f};

    auto sel = [&](float4 al) {
        return (hsel == 0) ? al.x : (hsel == 1) ? al.y : (hsel == 2) ? al.z : al.w;
    };
    auto consume = [&](uint4 v, float a) {
        f32x2 ap = {a, a};
        acc2[0] += ap * __builtin_amdgcn_cvt_pk_f32_fp8(v.x, false);
        acc2[1] += ap * __builtin_amdgcn_cvt_pk_f32_fp8(v.x, true);
        acc2[2] += ap * __builtin_amdgcn_cvt_pk_f32_fp8(v.y, false);
        acc2[3] += ap * __builtin_amdgcn_cvt_pk_f32_fp8(v.y, true);
        acc2[4] += ap * __builtin_amdgcn_cvt_pk_f32_fp8(v.z, false);
        acc2[5] += ap * __builtin_amdgcn_cvt_pk_f32_fp8(v.z, true);
        acc2[6] += ap * __builtin_amdgcn_cvt_pk_f32_fp8(v.w, false);
        acc2[7] += ap * __builtin_amdgcn_cvt_pk_f32_fp8(v.w, true);
    };

    int p = p0 + e;
    bool va = p < p1;
    bool vb = (p + EPI) < p1;
    float aa = 0.f, ab = 0.f;
    uint4 ua = make_uint4(0, 0, 0, 0), ub = make_uint4(0, 0, 0, 0);
    if (va) { aa = sel(alpha[p]);       ua = hp4[(size_t)esrc[p] * SL + sl]; }
    if (vb) { ab = sel(alpha[p + EPI]); ub = hp4[(size_t)esrc[p + EPI] * SL + sl]; }

    while (__any(va)) {
        int pa = p + 2 * EPI, pb = p + 3 * EPI;
        bool va2 = pa < p1, vb2 = pb < p1;
        float aa2 = 0.f, ab2 = 0.f;
        uint4 ua2 = make_uint4(0, 0, 0, 0), ub2 = make_uint4(0, 0, 0, 0);
        if (va2) { aa2 = sel(alpha[pa]); ua2 = hp4[(size_t)esrc[pa] * SL + sl]; }
        if (vb2) { ab2 = sel(alpha[pb]); ub2 = hp4[(size_t)esrc[pb] * SL + sl]; }
        if (va) consume(ua, aa);
        if (vb) consume(ub, ab);
        p = pa; va = va2; vb = vb2; aa = aa2; ab = ab2; ua = ua2; ub = ub2;
    }

    float acc[16];
#pragma unroll
    for (int j = 0; j < 8; j++) { acc[2 * j] = acc2[j][0]; acc[2 * j + 1] = acc2[j][1]; }

    // butterfly: sums EPI edge-groups AND the H heads in one pass (alpha carries 1/den/H)
#pragma unroll
    for (int off = 32; off >= HL; off >>= 1) {
#pragma unroll
        for (int j = 0; j < 16; j++) acc[j] += __shfl_xor(acc[j], off);
    }
    // lanes (mod HL) hold head-summed channels: lane class c2 = lane & (HL-1)
    const int c2 = lane & (HL - 1);
    const int cb = c2 * 16;                 // base output channel of this lane class
    float val[16];
    float s = 0.f;
    {
        float4 b0 = *(const float4*)(bias + cb);
        float4 b1 = *(const float4*)(bias + cb + 4);
        float4 b2 = *(const float4*)(bias + cb + 8);
        float4 b3 = *(const float4*)(bias + cb + 12);
        float bb[16] = {b0.x, b0.y, b0.z, b0.w, b1.x, b1.y, b1.z, b1.w,
                        b2.x, b2.y, b2.z, b2.w, b3.x, b3.y, b3.z, b3.w};
#pragma unroll
        for (int j = 0; j < 16; j++) {
            val[j] = fmaxf(acc[j] + bb[j], 0.f);
            s += val[j];
        }
    }
#pragma unroll
    for (int off = 1; off < HL; off <<= 1) s += __shfl_xor(s, off);
    float mu = s / DO;
    float q = 0.f;
#pragma unroll
    for (int j = 0; j < 16; j++) {
        val[j] -= mu;
        q += val[j] * val[j];
    }
#pragma unroll
    for (int off = 1; off < HL; off <<= 1) q += __shfl_xor(q, off);
    float rstd = rsqrtf(q / DO + LN_EPS);

    if (lane < HL) {
        float4 g0 = *(const float4*)(gamma + cb);
        float4 g1 = *(const float4*)(gamma + cb + 4);
        float4 g2 = *(const float4*)(gamma + cb + 8);
        float4 g3 = *(const float4*)(gamma + cb + 12);
        float4 e0 = *(const float4*)(beta + cb);
        float4 e1 = *(const float4*)(beta + cb + 4);
        float4 e2 = *(const float4*)(beta + cb + 8);
        float4 e3 = *(const float4*)(beta + cb + 12);
        float gg[16] = {g0.x, g0.y, g0.z, g0.w, g1.x, g1.y, g1.z, g1.w,
                        g2.x, g2.y, g2.z, g2.w, g3.x, g3.y, g3.z, g3.w};
        float ee[16] = {e0.x, e0.y, e0.z, e0.w, e1.x, e1.y, e1.z, e1.w,
                        e2.x, e2.y, e2.z, e2.w, e3.x, e3.y, e3.z, e3.w};
        float o[16];
#pragma unroll
        for (int j = 0; j < 16; j++) o[j] = val[j] * rstd * gg[j] + ee[j];
        if (RESID) {
            const uint4* pv = (const uint4*)(hprev + (size_t)n * DO + cb);
            uint4 r0 = pv[0], r1 = pv[1];
            unsigned rr[8] = {r0.x, r0.y, r0.z, r0.w, r1.x, r1.y, r1.z, r1.w};
#pragma unroll
            for (int j = 0; j < 8; j++) {
                o[2 * j]     += bf_lo(rr[j]);
                o[2 * j + 1] += bf_hi(rr[j]);
            }
        }
        unsigned w[8];
#pragma unroll
        for (int j = 0; j < 8; j++)
            w[j] = (unsigned)f2bf(o[2 * j]) | ((unsigned)f2bf(o[2 * j + 1]) << 16);
        uint4* op = (uint4*)(hout + (size_t)n * DO + cb);
        op[0] = make_uint4(w[0], w[1], w[2], w[3]);
        op[1] = make_uint4(w[4], w[5], w[6], w[7]);
    }
}

// ---------------- pooling (hierarchical) + readout ----------------
__global__ void pool_accum2(const ushort* __restrict__ h, const int* __restrict__ batch,
                            float* __restrict__ pooled, float* __restrict__ cnt) {
    __shared__ float lp[BG * 32];
    __shared__ float lc[BG];
    for (int i = threadIdx.x; i < BG * 32; i += blockDim.x) lp[i] = 0.f;
    if (threadIdx.x < BG) lc[threadIdx.x] = 0.f;
    __syncthreads();
    int c = threadIdx.x & 31;
    int rb = threadIdx.x >> 5;
    for (int n = blockIdx.x * 8 + rb; n < NN; n += gridDim.x * 8) {
        int b = batch[n];
        atomicAdd(&lp[b * 32 + c], bf2f((unsigned)h[(size_t)n * 32 + c]));
        if (c == 0) atomicAdd(&lc[b], 1.f);
    }
    __syncthreads();
    for (int i = threadIdx.x; i < BG * 32; i += blockDim.x) atomicAdd(&pooled[i], lp[i]);
    if (threadIdx.x < BG) atomicAdd(&cnt[threadIdx.x], lc[threadIdx.x]);
}

__global__ void final_out(const float* __restrict__ pooled, const float* __restrict__ cnt,
                          const float* __restrict__ Wo, const float* __restrict__ bo,
                          float* __restrict__ out) {
    int b = threadIdx.x;
    if (b < BG) {
        float inv = 1.f / fmaxf(cnt[b], 1.f);
        float acc = 0.f;
        for (int c = 0; c < 32; c++) acc += pooled[b * 32 + c] * inv * Wo[c];
        out[b] = acc + bo[0];
    }
}

// ---------------- host orchestration ----------------
extern "C" void kernel_launch(void* const* d_in, const int* in_sizes, int n_in,
                              void* d_out, int out_size, void* d_ws, size_t ws_size,
                              hipStream_t stream) {
    const float* x     = (const float*)d_in[0];
    const int*   ei    = (const int*)d_in[1];
    const int*   batch = (const int*)d_in[2];
    const float* Wi    = (const float*)d_in[3];
    const float* bi    = (const float*)d_in[4];
    const float* Wl[4]  = {(const float*)d_in[5],  (const float*)d_in[11], (const float*)d_in[17], (const float*)d_in[23]};
    const float* Asl[4] = {(const float*)d_in[6],  (const float*)d_in[12], (const float*)d_in[18], (const float*)d_in[24]};
    const float* Adl[4] = {(const float*)d_in[7],  (const float*)d_in[13], (const float*)d_in[19], (const float*)d_in[25]};
    const float* Bl[4]  = {(const float*)d_in[8],  (const float*)d_in[14], (const float*)d_in[20], (const float*)d_in[26]};
    const float* Gl[4]  = {(const float*)d_in[9],  (const float*)d_in[15], (const float*)d_in[21], (const float*)d_in[27]};
    const float* Bel[4] = {(const float*)d_in[10], (const float*)d_in[16], (const float*)d_in[22], (const float*)d_in[28]};
    const float* Wo = (const float*)d_in[29];
    const float* bo = (const float*)d_in[30];

    char* p = (char*)d_ws;
    auto take = [&](size_t bytes) -> void* {
        void* r = (void*)p;
        p += (bytes + 255) & ~(size_t)255;
        return r;
    };
    // activation buffers padded to NNP rows (GEMM A reads rows < NNP unguarded;
    // results for rows >= NN are discarded by store guards)
    ushort*   hAbf   = (ushort*)take((size_t)NNP * HID * 2);
    ushort*   hBbf   = (ushort*)take((size_t)NNP * HID * 2);
    uchar*    hproj  = (uchar*)take((size_t)NN * H * HID);      // fp8 e4m3
    ushort*   xpad   = (ushort*)take((size_t)NNP * 128 * 2);
    int*      rowptr = (int*)take((size_t)(NN + 1) * 4);
    int*      esrc   = (int*)take((size_t)ETOT * 4);
    float4*   alpha  = (float4*)take((size_t)ETOT * 16);
    ushort*   wti    = (ushort*)take((size_t)CWI * 2);
    ushort*   wt0    = (ushort*)take((size_t)CW0 * 2);
    ushort*   wt1    = (ushort*)take((size_t)CW1 * 2);
    ushort*   wt2    = (ushort*)take((size_t)CW2 * 2);
    ushort*   wt3    = (ushort*)take((size_t)CW3 * 2);
    // ---- contiguous zero region from here ----
    char*     zbase  = p;
    int*      deg    = (int*)take((size_t)NN * 4);
    int*      fill   = (int*)take((size_t)NN * 4);
    float*    pooled = (float*)take((size_t)BG * 32 * 4);
    float*    cnt    = (float*)take((size_t)BG * 4);
    float*    als[4], *ald[4];
    for (int l = 0; l < 4; l++) {
        als[l] = (float*)take((size_t)NN * H * 4);
        ald[l] = (float*)take((size_t)NN * H * 4);
    }
    const int zcount = (int)((p - zbase) / 4);
    (void)ws_size; (void)n_in; (void)in_sizes; (void)out_size;

    const int ZB = 256;
    const int egrid = (ETOT + ZB - 1) / ZB;
    const int mtiles = (NN + 63) / 64;       // 313
    const int sgrid = (NN * 64 + 255) / 256; // softmax: 1 wave per dst
    const int agrid = NN / 4;                // aggregate: 1 wave per dst, 4 waves/block

    // one zero kernel: deg, fill, pooled, cnt, all al buffers (incl. align pads)
    zero_u32<<<(zcount + ZB - 1) / ZB, ZB, 0, stream>>>((uint32_t*)zbase, zcount);
    // one convert kernel: xpad + weights + count_deg
    conv_all<<<(CALL + ZB - 1) / ZB, ZB, 0, stream>>>(x, Wi, Wl[0], Wl[1], Wl[2], Wl[3],
                                                      ei, deg,
                                                      xpad, wti, wt0, wt1, wt2, wt3);
    scan_kernel<<<1, 1024, 0, stream>>>(deg, rowptr);
    scatter_edges<<<egrid, ZB, 0, stream>>>(ei, rowptr, fill, esrc);

    // input layer: hAbf = relu(x @ Wi + bi)   (CT=2, y=2)
    gemm_mfma<128, 256, 2, true, false><<<dim3(mtiles, 2), 256, 0, stream>>>(
        xpad, wti, bi, hAbf, nullptr, nullptr, nullptr, nullptr, NN);

    // ---- level 0: 256 -> 256, residual ----  (CT=4, y=4: 1252 blocks)
    gemm_mfma<256, 1024, 4, false, true><<<dim3(mtiles, 4), 256, 0, stream>>>(
        hAbf, wt0, nullptr, hproj, Asl[0], Adl[0], als[0], ald[0], NN);
    softmax_csr<<<sgrid, 256, 0, stream>>>(rowptr, esrc, als[0], ald[0], alpha);
    aggregate<256, true><<<agrid, 256, 0, stream>>>(hproj, rowptr, esrc, alpha,
                                                    Bl[0], Gl[0], Bel[0], hAbf, hBbf);
    // ---- level 1: 256 -> 128 ----  (CT=4, y=2)
    gemm_mfma<256, 512, 4, false, true><<<dim3(mtiles, 2), 256, 0, stream>>>(
        hBbf, wt1, nullptr, hproj, Asl[1], Adl[1], als[1], ald[1], NN);
    softmax_csr<<<sgrid, 256, 0, stream>>>(rowptr, esrc, als[1], ald[1], alpha);
    aggregate<128, false><<<agrid, 256, 0, stream>>>(hproj, rowptr, esrc, alpha,
                                                     Bl[1], Gl[1], Bel[1], nullptr, hAbf);
    // ---- level 2: 128 -> 64 ----  (CT=2, y=2)
    gemm_mfma<128, 256, 2, false, true><<<dim3(mtiles, 2), 256, 0, stream>>>(
        hAbf, wt2, nullptr, hproj, Asl[2], Adl[2], als[2], ald[2], NN);
    softmax_csr<<<sgrid, 256, 0, stream>>>(rowptr, esrc, als[2], ald[2], alpha);
    aggregate<64, false><<<agrid, 256, 0, stream>>>(hproj, rowptr, esrc, alpha,
                                                    Bl[2], Gl[2], Bel[2], nullptr, hBbf);
    // ---- level 3: 64 -> 32 ----  (CT=1, y=2)
    gemm_mfma<64, 128, 1, false, true><<<dim3(mtiles, 2), 256, 0, stream>>>(
        hBbf, wt3, nullptr, hproj, Asl[3], Adl[3], als[3], ald[3], NN);
    softmax_csr<<<sgrid, 256, 0, stream>>>(rowptr, esrc, als[3], ald[3], alpha);
    aggregate<32, false><<<agrid, 256, 0, stream>>>(hproj, rowptr, esrc, alpha,
                                                    Bl[3], Gl[3], Bel[3], nullptr, hAbf);

    // ---- pooling + readout ----
    pool_accum2<<<80, 256, 0, stream>>>(hAbf, batch, pooled, cnt);
    final_out<<<1, 64, 0, stream>>>(pooled, cnt, Wo, bo, (float*)d_out);
}

// Round 14
// 523.669 us; speedup vs baseline: 1.1162x; 1.1162x over previous
//
#include <hip/hip_runtime.h>
#include <hip/hip_bf16.h>
#include <cstdint>

// ---- problem constants (HierarchicalBrainGNN) ----
constexpr int NN   = 20000;          // nodes
constexpr int NNP  = 20032;          // padded to 313*64 (GEMM reads A rows unguarded)
constexpr int NE   = 320000;         // edges before self loops
constexpr int ETOT = NE + NN;        // with self loops
constexpr int BG   = 8;              // graphs
constexpr int FIN  = 100;
constexpr int HID  = 256;
constexpr int H    = 4;              // heads
constexpr float SLOPE  = 0.2f;
constexpr float LN_EPS = 1e-5f;

#define DEVFN __device__ __forceinline__

typedef __bf16 bf16x8 __attribute__((ext_vector_type(8)));
typedef float  f32x4  __attribute__((ext_vector_type(4)));
typedef float  f32x2  __attribute__((ext_vector_type(2)));

DEVFN float lrelu(float v) { return v > 0.f ? v : SLOPE * v; }
// fp32 -> bf16 bits, round-nearest-even (finite inputs)
DEVFN ushort f2bf(float f) {
    unsigned u = __float_as_uint(f);
    return (ushort)((u + 0x7fffu + ((u >> 16) & 1u)) >> 16);
}
DEVFN float bf_lo(unsigned u) { return __uint_as_float(u << 16); }
DEVFN float bf_hi(unsigned u) { return __uint_as_float(u & 0xffff0000u); }
DEVFN float bf2f(unsigned u) { return __uint_as_float(u << 16); }

// ---------------- utility ----------------
__global__ void zero_u32(uint32_t* __restrict__ p, int n) {
    int i = blockIdx.x * blockDim.x + threadIdx.x;
    if (i < n) p[i] = 0u;
}

// single-block scan, 4 values/thread (int4), wave-shuffle based; 5 chunks of 4096
__global__ void scan_kernel(const int* __restrict__ deg, int* __restrict__ rowptr) {
    __shared__ int wsum[16];
    __shared__ int woff[16];
    __shared__ int ctot;
    const int lane = threadIdx.x & 63;
    const int wv   = threadIdx.x >> 6;
    const int4* deg4 = (const int4*)deg;        // NN/4 = 5000 int4 (deg 256-aligned)
    int carry = 0;
    for (int base4 = 0; base4 < NN / 4; base4 += 1024) {
        int i4 = base4 + threadIdx.x;
        int4 v = make_int4(0, 0, 0, 0);
        if (i4 < NN / 4) v = deg4[i4];
        int t0 = v.x, t1 = t0 + v.y, t2 = t1 + v.z, t3 = t2 + v.w;  // thread-local incl
        int s = t3;
#pragma unroll
        for (int off = 1; off < 64; off <<= 1) {
            int t = __shfl_up(s, off);
            if (lane >= off) s += t;
        }
        if (lane == 63) wsum[wv] = s;
        __syncthreads();
        if (wv == 0 && lane < 16) {
            int ws = wsum[lane];
            int sc = ws;
#pragma unroll
            for (int off = 1; off < 16; off <<= 1) {
                int t = __shfl_up(sc, off);
                if (lane >= off) sc += t;
            }
            woff[lane] = sc - ws;
            if (lane == 15) ctot = sc;
        }
        __syncthreads();
        if (i4 < NN / 4) {
            int be = carry + woff[wv] + (s - t3);   // exclusive prefix of this thread's 4
            rowptr[4 * i4 + 0] = be;
            rowptr[4 * i4 + 1] = be + t0;
            rowptr[4 * i4 + 2] = be + t1;
            rowptr[4 * i4 + 3] = be + t2;
        }
        carry += ctot;
        __syncthreads();
    }
    if (threadIdx.x == 0) rowptr[NN] = carry;
}

__global__ void scatter_edges(const int* __restrict__ ei, const int* __restrict__ rowptr,
                              int* __restrict__ fill, int* __restrict__ esrc) {
    int k = blockIdx.x * blockDim.x + threadIdx.x;
    if (k >= ETOT) return;
    int s, d;
    if (k < NE) { s = ei[k]; d = ei[NE + k]; }
    else        { s = k - NE; d = k - NE; }
    int pos = rowptr[d] + atomicAdd(&fill[d], 1);
    esrc[pos] = s;
}

// --- fused convert (+count_deg): xpad + 5 transposed bf16 weights + degree count ---
constexpr int CXN  = NN * 128;
constexpr int CWI  = 256 * 128;
constexpr int CW0  = 1024 * 256;
constexpr int CW1  = 512 * 256;
constexpr int CW2  = 256 * 128;
constexpr int CW3  = 128 * 64;
constexpr int CTOT = CXN + CWI + CW0 + CW1 + CW2 + CW3;
constexpr int CALL = CTOT + ETOT;          // + count_deg range

__global__ void conv_all(const float* __restrict__ x, const float* __restrict__ Wi,
                         const float* __restrict__ W0, const float* __restrict__ W1,
                         const float* __restrict__ W2, const float* __restrict__ W3,
                         const int* __restrict__ ei, int* __restrict__ deg,
                         ushort* __restrict__ xpad, ushort* __restrict__ wti,
                         ushort* __restrict__ wt0, ushort* __restrict__ wt1,
                         ushort* __restrict__ wt2, ushort* __restrict__ wt3) {
    int id = blockIdx.x * blockDim.x + threadIdx.x;
    if (id < CXN) {
        int n = id >> 7, k = id & 127;
        xpad[id] = (k < FIN) ? f2bf(x[(size_t)n * FIN + k]) : (ushort)0;
        return;
    }
    id -= CXN;
    if (id < CWI) { int n = id / 128, k = id - n * 128;
        wti[id] = (k < FIN) ? f2bf(Wi[(size_t)k * 256 + n]) : (ushort)0; return; }
    id -= CWI;
    if (id < CW0) { int n = id / 256, k = id - n * 256;
        wt0[id] = f2bf(W0[(size_t)k * 1024 + n]); return; }
    id -= CW0;
    if (id < CW1) { int n = id / 256, k = id - n * 256;
        wt1[id] = f2bf(W1[(size_t)k * 512 + n]); return; }
    id -= CW1;
    if (id < CW2) { int n = id / 128, k = id - n * 128;
        wt2[id] = f2bf(W2[(size_t)k * 256 + n]); return; }
    id -= CW2;
    if (id < CW3) { int n = id / 64, k = id - n * 64;
        wt3[id] = f2bf(W3[(size_t)k * 128 + n]); return; }
    id -= CW3;
    if (id < ETOT) {     // count_deg (deg pre-zeroed by the zero kernel)
        int d = (id < NE) ? ei[NE + id] : (id - NE);
        atomicAdd(&deg[d], 1);
    }
}

// ---------------- MFMA bf16 GEMM + fused attention-logit epilogue --------------------
// (round-12 version: A fragments read DIRECTLY from global through L1; B staged in LDS
//  straight from global — NO register double-buffer, which the compiler spilled to
//  scratch in round 13: WRITE_SIZE 180 MB, VGPR 52.)
// CT col-tiles per block (B restaged per tile). A buffers padded to NNP rows.
// if !AL: Cout = bf16[M,NC] = relu(A@Wt^T + bias) (input layer)
// if  AL: Cout = fp8 e4m3 [M,NC] (hproj); al_s/al_d from exact fp32 accumulators
// A-frag: A[m=lane&15][k=quad*8+j]; B-frag: B[k][n=lane&15];
// D: col=lane&15, row=quad*4+reg  (verified round 2)
template <int K, int NC, int CT, bool BR, bool AL>
__launch_bounds__(256)
__global__ void gemm_mfma(const ushort* __restrict__ A, const ushort* __restrict__ Wt,
                          const float* __restrict__ bias, void* __restrict__ Cout,
                          const float* __restrict__ a_s, const float* __restrict__ a_d,
                          float* __restrict__ al_s, float* __restrict__ al_d, int M) {
    constexpr int LDK = K + 8;
    constexpr int DO_AL = NC / H;
    __shared__ ushort Bs[64 * LDK];
    const int row0 = blockIdx.x * 64;
    const int colbase = blockIdx.y * (64 * CT);
    const int tid = threadIdx.x;
    constexpr int CH = K / 8;
    const int wave = tid >> 6;
    const int lane = tid & 63;
    const int m = lane & 15;
    const int q = lane >> 4;
    const ushort* Ap  = A + (size_t)(row0 + wave * 16 + m) * K + q * 8;  // rows < NNP
    const ushort* bp0 = &Bs[(0 * 16 + m) * LDK + q * 8];
    const ushort* bp1 = &Bs[(1 * 16 + m) * LDK + q * 8];
    const ushort* bp2 = &Bs[(2 * 16 + m) * LDK + q * 8];
    const ushort* bp3 = &Bs[(3 * 16 + m) * LDK + q * 8];
    const int grow0 = row0 + wave * 16 + q * 4;

    for (int ct = 0; ct < CT; ct++) {
        const int col0 = colbase + ct * 64;
        for (int c = tid; c < 64 * CH; c += 256) {
            int r = c / CH, cc = c - r * CH;
            *(uint4*)(&Bs[r * LDK + cc * 8]) =
                *(const uint4*)(Wt + (size_t)(col0 + r) * K + cc * 8);
        }
        __syncthreads();
        f32x4 acc0 = {0.f, 0.f, 0.f, 0.f}, acc1 = acc0, acc2 = acc0, acc3 = acc0;
#pragma unroll
        for (int kk = 0; kk < K / 32; kk++) {
            bf16x8 a = *(const bf16x8*)(Ap + kk * 32);
            acc0 = __builtin_amdgcn_mfma_f32_16x16x32_bf16(a, *(const bf16x8*)(bp0 + kk * 32), acc0, 0, 0, 0);
            acc1 = __builtin_amdgcn_mfma_f32_16x16x32_bf16(a, *(const bf16x8*)(bp1 + kk * 32), acc1, 0, 0, 0);
            acc2 = __builtin_amdgcn_mfma_f32_16x16x32_bf16(a, *(const bf16x8*)(bp2 + kk * 32), acc2, 0, 0, 0);
            acc3 = __builtin_amdgcn_mfma_f32_16x16x32_bf16(a, *(const bf16x8*)(bp3 + kk * 32), acc3, 0, 0, 0);
        }
        if (!AL) {
            ushort* Cb = (ushort*)Cout + (size_t)grow0 * NC + col0 + m;
            float b0 = 0, b1 = 0, b2 = 0, b3 = 0;
            if (BR) {
                b0 = bias[col0 + m];      b1 = bias[col0 + m + 16];
                b2 = bias[col0 + m + 32]; b3 = bias[col0 + m + 48];
            }
#pragma unroll
            for (int r = 0; r < 4; r++) {
                if (grow0 + r < M) {
                    float v0 = acc0[r], v1 = acc1[r], v2 = acc2[r], v3 = acc3[r];
                    if (BR) {
                        v0 = fmaxf(v0 + b0, 0.f); v1 = fmaxf(v1 + b1, 0.f);
                        v2 = fmaxf(v2 + b2, 0.f); v3 = fmaxf(v3 + b3, 0.f);
                    }
                    Cb[(size_t)r * NC + 0]  = f2bf(v0);
                    Cb[(size_t)r * NC + 16] = f2bf(v1);
                    Cb[(size_t)r * NC + 32] = f2bf(v2);
                    Cb[(size_t)r * NC + 48] = f2bf(v3);
                }
            }
        } else {
            uchar* Cb = (uchar*)Cout + (size_t)grow0 * NC + col0 + m;
#pragma unroll
            for (int r = 0; r < 4; r++) {
                if (grow0 + r < M) {
                    int pk01 = __builtin_amdgcn_cvt_pk_fp8_f32(acc0[r], acc1[r], 0, false);
                    int pk23 = __builtin_amdgcn_cvt_pk_fp8_f32(acc2[r], acc3[r], 0, false);
                    Cb[(size_t)r * NC + 0]  = (uchar)(pk01 & 0xff);
                    Cb[(size_t)r * NC + 16] = (uchar)((pk01 >> 8) & 0xff);
                    Cb[(size_t)r * NC + 32] = (uchar)(pk23 & 0xff);
                    Cb[(size_t)r * NC + 48] = (uchar)((pk23 >> 8) & 0xff);
                }
            }
            float asv[4], adv[4];
#pragma unroll
            for (int t = 0; t < 4; t++) {
                int gc = col0 + m + 16 * t;
                asv[t] = a_s[gc];
                adv[t] = a_d[gc];
            }
            const int h_lo = col0 / DO_AL;
            const int h_hi = (col0 + 32) / DO_AL;
#pragma unroll
            for (int r = 0; r < 4; r++) {
                float ps0 = acc0[r] * asv[0] + acc1[r] * asv[1];
                float ps1 = acc2[r] * asv[2] + acc3[r] * asv[3];
                float pd0 = acc0[r] * adv[0] + acc1[r] * adv[1];
                float pd1 = acc2[r] * adv[2] + acc3[r] * adv[3];
#pragma unroll
                for (int off = 1; off < 16; off <<= 1) {
                    ps0 += __shfl_xor(ps0, off);
                    ps1 += __shfl_xor(ps1, off);
                    pd0 += __shfl_xor(pd0, off);
                    pd1 += __shfl_xor(pd1, off);
                }
                if (m == 0 && grow0 + r < M) {
                    if (h_lo == h_hi) {
                        atomicAdd(&al_s[(grow0 + r) * H + h_lo], ps0 + ps1);
                        atomicAdd(&al_d[(grow0 + r) * H + h_lo], pd0 + pd1);
                    } else {
                        atomicAdd(&al_s[(grow0 + r) * H + h_lo], ps0);
                        atomicAdd(&al_s[(grow0 + r) * H + h_hi], ps1);
                        atomicAdd(&al_d[(grow0 + r) * H + h_lo], pd0);
                        atomicAdd(&al_d[(grow0 + r) * H + h_hi], pd1);
                    }
                }
            }
        }
        __syncthreads();   // all waves done reading Bs before restage
    }
}

// ---------------- fused segment softmax: one wave per dst, writes normalized alpha ----------
__global__ void softmax_csr(const int* __restrict__ rowptr, const int* __restrict__ esrc,
                            const float* __restrict__ al_s, const float* __restrict__ al_d,
                            float4* __restrict__ alpha) {
    int wid = (blockIdx.x * blockDim.x + threadIdx.x) >> 6;
    int lane = threadIdx.x & 63;
    if (wid >= NN) return;
    int p0 = rowptr[wid], p1 = rowptr[wid + 1];
    float4 d4 = ((const float4*)al_d)[wid];
    float m0 = -1e30f, m1 = -1e30f, m2 = -1e30f, m3 = -1e30f;
    for (int p = p0 + lane; p < p1; p += 64) {
        int s = esrc[p];
        float4 s4 = ((const float4*)al_s)[s];
        m0 = fmaxf(m0, lrelu(s4.x + d4.x));
        m1 = fmaxf(m1, lrelu(s4.y + d4.y));
        m2 = fmaxf(m2, lrelu(s4.z + d4.z));
        m3 = fmaxf(m3, lrelu(s4.w + d4.w));
    }
#pragma unroll
    for (int off = 32; off > 0; off >>= 1) {
        m0 = fmaxf(m0, __shfl_xor(m0, off));
        m1 = fmaxf(m1, __shfl_xor(m1, off));
        m2 = fmaxf(m2, __shfl_xor(m2, off));
        m3 = fmaxf(m3, __shfl_xor(m3, off));
    }
    float s0 = 0.f, s1 = 0.f, s2 = 0.f, s3 = 0.f;
    for (int p = p0 + lane; p < p1; p += 64) {
        int s = esrc[p];
        float4 s4 = ((const float4*)al_s)[s];
        s0 += __expf(lrelu(s4.x + d4.x) - m0);
        s1 += __expf(lrelu(s4.y + d4.y) - m1);
        s2 += __expf(lrelu(s4.z + d4.z) - m2);
        s3 += __expf(lrelu(s4.w + d4.w) - m3);
    }
#pragma unroll
    for (int off = 32; off > 0; off >>= 1) {
        s0 += __shfl_xor(s0, off);
        s1 += __shfl_xor(s1, off);
        s2 += __shfl_xor(s2, off);
        s3 += __shfl_xor(s3, off);
    }
    // fold head-mean 1/H into alpha
    float i0 = 0.25f / (s0 + 1e-16f), i1 = 0.25f / (s1 + 1e-16f);
    float i2 = 0.25f / (s2 + 1e-16f), i3 = 0.25f / (s3 + 1e-16f);
    for (int p = p0 + lane; p < p1; p += 64) {
        int s = esrc[p];
        float4 s4 = ((const float4*)al_s)[s];
        alpha[p] = make_float4(__expf(lrelu(s4.x + d4.x) - m0) * i0,
                               __expf(lrelu(s4.y + d4.y) - m1) * i1,
                               __expf(lrelu(s4.z + d4.z) - m2) * i2,
                               __expf(lrelu(s4.w + d4.w) - m3) * i3);
    }
}

// ------- WAVE-PER-NODE aggregate: fp8 gather, 2-wide x 2-deep pipeline -------
// Zero LDS, zero __syncthreads. 4 independent waves/block (one node each).
// SL = H*DO/16 lanes per edge row (one uint4 = 16 fp8 ch per lane);
// EPI = 64/SL edge groups; 2 edges consumed + 2 prefetched per iteration.
template <int DO, bool RESID>
__launch_bounds__(256)
__global__ void aggregate(const uchar* __restrict__ hproj, const int* __restrict__ rowptr,
                          const int* __restrict__ esrc, const float4* __restrict__ alpha,
                          const float* __restrict__ bias, const float* __restrict__ gamma,
                          const float* __restrict__ beta, const ushort* __restrict__ hprev,
                          ushort* __restrict__ hout) {
    constexpr int HDO = H * DO;
    constexpr int SL  = HDO / 16;          // lanes per edge row: 64/32/16/8
    constexpr int EPI = 64 / SL;           // edge groups per wave: 1/2/4/8
    constexpr int HL  = DO / 16;           // lane classes: 16/8/4/2
    const int wave = threadIdx.x >> 6;
    const int lane = threadIdx.x & 63;
    const int n = blockIdx.x * 4 + wave;   // NN=20000 = 5000*4 exactly
    const int e  = lane / SL;
    const int sl = lane - e * SL;
    const int hsel = sl / HL;              // head of this lane's 16 channels
    const int p0 = rowptr[n], p1 = rowptr[n + 1];
    const uint4* hp4 = (const uint4*)hproj;

    f32x2 acc2[8];
#pragma unroll
    for (int j = 0; j < 8; j++) acc2[j] = f32x2{0.f, 0.f};

    auto sel = [&](float4 al) {
        return (hsel == 0) ? al.x : (hsel == 1) ? al.y : (hsel == 2) ? al.z : al.w;
    };
    auto consume = [&](uint4 v, float a) {
        f32x2 ap = {a, a};
        acc2[0] += ap * __builtin_amdgcn_cvt_pk_f32_fp8(v.x, false);
        acc2[1] += ap * __builtin_amdgcn_cvt_pk_f32_fp8(v.x, true);
        acc2[2] += ap * __builtin_amdgcn_cvt_pk_f32_fp8(v.y, false);
        acc2[3] += ap * __builtin_amdgcn_cvt_pk_f32_fp8(v.y, true);
        acc2[4] += ap * __builtin_amdgcn_cvt_pk_f32_fp8(v.z, false);
        acc2[5] += ap * __builtin_amdgcn_cvt_pk_f32_fp8(v.z, true);
        acc2[6] += ap * __builtin_amdgcn_cvt_pk_f32_fp8(v.w, false);
        acc2[7] += ap * __builtin_amdgcn_cvt_pk_f32_fp8(v.w, true);
    };

    int p = p0 + e;
    bool va = p < p1;
    bool vb = (p + EPI) < p1;
    float aa = 0.f, ab = 0.f;
    uint4 ua = make_uint4(0, 0, 0, 0), ub = make_uint4(0, 0, 0, 0);
    if (va) { aa = sel(alpha[p]);       ua = hp4[(size_t)esrc[p] * SL + sl]; }
    if (vb) { ab = sel(alpha[p + EPI]); ub = hp4[(size_t)esrc[p + EPI] * SL + sl]; }

    while (__any(va)) {
        int pa = p + 2 * EPI, pb = p + 3 * EPI;
        bool va2 = pa < p1, vb2 = pb < p1;
        float aa2 = 0.f, ab2 = 0.f;
        uint4 ua2 = make_uint4(0, 0, 0, 0), ub2 = make_uint4(0, 0, 0, 0);
        if (va2) { aa2 = sel(alpha[pa]); ua2 = hp4[(size_t)esrc[pa] * SL + sl]; }
        if (vb2) { ab2 = sel(alpha[pb]); ub2 = hp4[(size_t)esrc[pb] * SL + sl]; }
        if (va) consume(ua, aa);
        if (vb) consume(ub, ab);
        p = pa; va = va2; vb = vb2; aa = aa2; ab = ab2; ua = ua2; ub = ub2;
    }

    float acc[16];
#pragma unroll
    for (int j = 0; j < 8; j++) { acc[2 * j] = acc2[j][0]; acc[2 * j + 1] = acc2[j][1]; }

    // butterfly: sums EPI edge-groups AND the H heads in one pass (alpha carries 1/den/H)
#pragma unroll
    for (int off = 32; off >= HL; off >>= 1) {
#pragma unroll
        for (int j = 0; j < 16; j++) acc[j] += __shfl_xor(acc[j], off);
    }
    // lanes (mod HL) hold head-summed channels: lane class c2 = lane & (HL-1)
    const int c2 = lane & (HL - 1);
    const int cb = c2 * 16;                 // base output channel of this lane class
    float val[16];
    float s = 0.f;
    {
        float4 b0 = *(const float4*)(bias + cb);
        float4 b1 = *(const float4*)(bias + cb + 4);
        float4 b2 = *(const float4*)(bias + cb + 8);
        float4 b3 = *(const float4*)(bias + cb + 12);
        float bb[16] = {b0.x, b0.y, b0.z, b0.w, b1.x, b1.y, b1.z, b1.w,
                        b2.x, b2.y, b2.z, b2.w, b3.x, b3.y, b3.z, b3.w};
#pragma unroll
        for (int j = 0; j < 16; j++) {
            val[j] = fmaxf(acc[j] + bb[j], 0.f);
            s += val[j];
        }
    }
#pragma unroll
    for (int off = 1; off < HL; off <<= 1) s += __shfl_xor(s, off);
    float mu = s / DO;
    float q = 0.f;
#pragma unroll
    for (int j = 0; j < 16; j++) {
        val[j] -= mu;
        q += val[j] * val[j];
    }
#pragma unroll
    for (int off = 1; off < HL; off <<= 1) q += __shfl_xor(q, off);
    float rstd = rsqrtf(q / DO + LN_EPS);

    if (lane < HL) {
        float4 g0 = *(const float4*)(gamma + cb);
        float4 g1 = *(const float4*)(gamma + cb + 4);
        float4 g2 = *(const float4*)(gamma + cb + 8);
        float4 g3 = *(const float4*)(gamma + cb + 12);
        float4 e0 = *(const float4*)(beta + cb);
        float4 e1 = *(const float4*)(beta + cb + 4);
        float4 e2 = *(const float4*)(beta + cb + 8);
        float4 e3 = *(const float4*)(beta + cb + 12);
        float gg[16] = {g0.x, g0.y, g0.z, g0.w, g1.x, g1.y, g1.z, g1.w,
                        g2.x, g2.y, g2.z, g2.w, g3.x, g3.y, g3.z, g3.w};
        float ee[16] = {e0.x, e0.y, e0.z, e0.w, e1.x, e1.y, e1.z, e1.w,
                        e2.x, e2.y, e2.z, e2.w, e3.x, e3.y, e3.z, e3.w};
        float o[16];
#pragma unroll
        for (int j = 0; j < 16; j++) o[j] = val[j] * rstd * gg[j] + ee[j];
        if (RESID) {
            const uint4* pv = (const uint4*)(hprev + (size_t)n * DO + cb);
            uint4 r0 = pv[0], r1 = pv[1];
            unsigned rr[8] = {r0.x, r0.y, r0.z, r0.w, r1.x, r1.y, r1.z, r1.w};
#pragma unroll
            for (int j = 0; j < 8; j++) {
                o[2 * j]     += bf_lo(rr[j]);
                o[2 * j + 1] += bf_hi(rr[j]);
            }
        }
        unsigned w[8];
#pragma unroll
        for (int j = 0; j < 8; j++)
            w[j] = (unsigned)f2bf(o[2 * j]) | ((unsigned)f2bf(o[2 * j + 1]) << 16);
        uint4* op = (uint4*)(hout + (size_t)n * DO + cb);
        op[0] = make_uint4(w[0], w[1], w[2], w[3]);
        op[1] = make_uint4(w[4], w[5], w[6], w[7]);
    }
}

// ---------------- pooling (hierarchical) + readout ----------------
__global__ void pool_accum2(const ushort* __restrict__ h, const int* __restrict__ batch,
                            float* __restrict__ pooled, float* __restrict__ cnt) {
    __shared__ float lp[BG * 32];
    __shared__ float lc[BG];
    for (int i = threadIdx.x; i < BG * 32; i += blockDim.x) lp[i] = 0.f;
    if (threadIdx.x < BG) lc[threadIdx.x] = 0.f;
    __syncthreads();
    int c = threadIdx.x & 31;
    int rb = threadIdx.x >> 5;
    for (int n = blockIdx.x * 8 + rb; n < NN; n += gridDim.x * 8) {
        int b = batch[n];
        atomicAdd(&lp[b * 32 + c], bf2f((unsigned)h[(size_t)n * 32 + c]));
        if (c == 0) atomicAdd(&lc[b], 1.f);
    }
    __syncthreads();
    for (int i = threadIdx.x; i < BG * 32; i += blockDim.x) atomicAdd(&pooled[i], lp[i]);
    if (threadIdx.x < BG) atomicAdd(&cnt[threadIdx.x], lc[threadIdx.x]);
}

__global__ void final_out(const float* __restrict__ pooled, const float* __restrict__ cnt,
                          const float* __restrict__ Wo, const float* __restrict__ bo,
                          float* __restrict__ out) {
    int b = threadIdx.x;
    if (b < BG) {
        float inv = 1.f / fmaxf(cnt[b], 1.f);
        float acc = 0.f;
        for (int c = 0; c < 32; c++) acc += pooled[b * 32 + c] * inv * Wo[c];
        out[b] = acc + bo[0];
    }
}

// ---------------- host orchestration ----------------
extern "C" void kernel_launch(void* const* d_in, const int* in_sizes, int n_in,
                              void* d_out, int out_size, void* d_ws, size_t ws_size,
                              hipStream_t stream) {
    const float* x     = (const float*)d_in[0];
    const int*   ei    = (const int*)d_in[1];
    const int*   batch = (const int*)d_in[2];
    const float* Wi    = (const float*)d_in[3];
    const float* bi    = (const float*)d_in[4];
    const float* Wl[4]  = {(const float*)d_in[5],  (const float*)d_in[11], (const float*)d_in[17], (const float*)d_in[23]};
    const float* Asl[4] = {(const float*)d_in[6],  (const float*)d_in[12], (const float*)d_in[18], (const float*)d_in[24]};
    const float* Adl[4] = {(const float*)d_in[7],  (const float*)d_in[13], (const float*)d_in[19], (const float*)d_in[25]};
    const float* Bl[4]  = {(const float*)d_in[8],  (const float*)d_in[14], (const float*)d_in[20], (const float*)d_in[26]};
    const float* Gl[4]  = {(const float*)d_in[9],  (const float*)d_in[15], (const float*)d_in[21], (const float*)d_in[27]};
    const float* Bel[4] = {(const float*)d_in[10], (const float*)d_in[16], (const float*)d_in[22], (const float*)d_in[28]};
    const float* Wo = (const float*)d_in[29];
    const float* bo = (const float*)d_in[30];

    char* p = (char*)d_ws;
    auto take = [&](size_t bytes) -> void* {
        void* r = (void*)p;
        p += (bytes + 255) & ~(size_t)255;
        return r;
    };
    // activation buffers padded to NNP rows (GEMM A reads rows < NNP unguarded;
    // results for rows >= NN are discarded by store guards)
    ushort*   hAbf   = (ushort*)take((size_t)NNP * HID * 2);
    ushort*   hBbf   = (ushort*)take((size_t)NNP * HID * 2);
    uchar*    hproj  = (uchar*)take((size_t)NN * H * HID);      // fp8 e4m3
    ushort*   xpad   = (ushort*)take((size_t)NNP * 128 * 2);
    int*      rowptr = (int*)take((size_t)(NN + 1) * 4);
    int*      esrc   = (int*)take((size_t)ETOT * 4);
    float4*   alpha  = (float4*)take((size_t)ETOT * 16);
    ushort*   wti    = (ushort*)take((size_t)CWI * 2);
    ushort*   wt0    = (ushort*)take((size_t)CW0 * 2);
    ushort*   wt1    = (ushort*)take((size_t)CW1 * 2);
    ushort*   wt2    = (ushort*)take((size_t)CW2 * 2);
    ushort*   wt3    = (ushort*)take((size_t)CW3 * 2);
    // ---- contiguous zero region from here ----
    char*     zbase  = p;
    int*      deg    = (int*)take((size_t)NN * 4);
    int*      fill   = (int*)take((size_t)NN * 4);
    float*    pooled = (float*)take((size_t)BG * 32 * 4);
    float*    cnt    = (float*)take((size_t)BG * 4);
    float*    als[4], *ald[4];
    for (int l = 0; l < 4; l++) {
        als[l] = (float*)take((size_t)NN * H * 4);
        ald[l] = (float*)take((size_t)NN * H * 4);
    }
    const int zcount = (int)((p - zbase) / 4);
    (void)ws_size; (void)n_in; (void)in_sizes; (void)out_size;

    const int ZB = 256;
    const int egrid = (ETOT + ZB - 1) / ZB;
    const int mtiles = (NN + 63) / 64;       // 313
    const int sgrid = (NN * 64 + 255) / 256; // softmax: 1 wave per dst
    const int agrid = NN / 4;                // aggregate: 1 wave per dst, 4 waves/block

    // one zero kernel: deg, fill, pooled, cnt, all al buffers (incl. align pads)
    zero_u32<<<(zcount + ZB - 1) / ZB, ZB, 0, stream>>>((uint32_t*)zbase, zcount);
    // one convert kernel: xpad + weights + count_deg
    conv_all<<<(CALL + ZB - 1) / ZB, ZB, 0, stream>>>(x, Wi, Wl[0], Wl[1], Wl[2], Wl[3],
                                                      ei, deg,
                                                      xpad, wti, wt0, wt1, wt2, wt3);
    scan_kernel<<<1, 1024, 0, stream>>>(deg, rowptr);
    scatter_edges<<<egrid, ZB, 0, stream>>>(ei, rowptr, fill, esrc);

    // input layer: hAbf = relu(x @ Wi + bi)   (CT=2, y=2)
    gemm_mfma<128, 256, 2, true, false><<<dim3(mtiles, 2), 256, 0, stream>>>(
        xpad, wti, bi, hAbf, nullptr, nullptr, nullptr, nullptr, NN);

    // ---- level 0: 256 -> 256, residual ----  (CT=4, y=4: 1252 blocks)
    gemm_mfma<256, 1024, 4, false, true><<<dim3(mtiles, 4), 256, 0, stream>>>(
        hAbf, wt0, nullptr, hproj, Asl[0], Adl[0], als[0], ald[0], NN);
    softmax_csr<<<sgrid, 256, 0, stream>>>(rowptr, esrc, als[0], ald[0], alpha);
    aggregate<256, true><<<agrid, 256, 0, stream>>>(hproj, rowptr, esrc, alpha,
                                                    Bl[0], Gl[0], Bel[0], hAbf, hBbf);
    // ---- level 1: 256 -> 128 ----  (CT=4, y=2)
    gemm_mfma<256, 512, 4, false, true><<<dim3(mtiles, 2), 256, 0, stream>>>(
        hBbf, wt1, nullptr, hproj, Asl[1], Adl[1], als[1], ald[1], NN);
    softmax_csr<<<sgrid, 256, 0, stream>>>(rowptr, esrc, als[1], ald[1], alpha);
    aggregate<128, false><<<agrid, 256, 0, stream>>>(hproj, rowptr, esrc, alpha,
                                                     Bl[1], Gl[1], Bel[1], nullptr, hAbf);
    // ---- level 2: 128 -> 64 ----  (CT=2, y=2)
    gemm_mfma<128, 256, 2, false, true><<<dim3(mtiles, 2), 256, 0, stream>>>(
        hAbf, wt2, nullptr, hproj, Asl[2], Adl[2], als[2], ald[2], NN);
    softmax_csr<<<sgrid, 256, 0, stream>>>(rowptr, esrc, als[2], ald[2], alpha);
    aggregate<64, false><<<agrid, 256, 0, stream>>>(hproj, rowptr, esrc, alpha,
                                                    Bl[2], Gl[2], Bel[2], nullptr, hBbf);
    // ---- level 3: 64 -> 32 ----  (CT=1, y=2)
    gemm_mfma<64, 128, 1, false, true><<<dim3(mtiles, 2), 256, 0, stream>>>(
        hBbf, wt3, nullptr, hproj, Asl[3], Adl[3], als[3], ald[3], NN);
    softmax_csr<<<sgrid, 256, 0, stream>>>(rowptr, esrc, als[3], ald[3], alpha);
    aggregate<32, false><<<agrid, 256, 0, stream>>>(hproj, rowptr, esrc, alpha,
                                                    Bl[3], Gl[3], Bel[3], nullptr, hAbf);

    // ---- pooling + readout ----
    pool_accum2<<<80, 256, 0, stream>>>(hAbf, batch, pooled, cnt);
    final_out<<<1, 64, 0, stream>>>(pooled, cnt, Wo, bo, (float*)d_out);
}